// Round 7
// baseline (300.072 us; speedup 1.0000x reference)
//
#include <hip/hip_runtime.h>

typedef __attribute__((ext_vector_type(4))) float f32x4;
typedef __attribute__((ext_vector_type(8))) short short8;

__device__ __forceinline__ unsigned short f2bf(float f) {
  unsigned int u = __float_as_uint(f);
  u += 0x7fff + ((u >> 16) & 1);   // round-to-nearest-even
  return (unsigned short)(u >> 16);
}

// ---------------- cast fp32 -> bf16 (stored as ushort), 4 elems/thread ----------------
__global__ __launch_bounds__(256) void cast_kernel(const float* __restrict__ in,
                                                   unsigned short* __restrict__ out,
                                                   int n4) {
  int i = blockIdx.x * 256 + threadIdx.x;
  if (i >= n4) return;
  float4 v = ((const float4*)in)[i];
  ushort4 o;
  o.x = f2bf(v.x); o.y = f2bf(v.y); o.z = f2bf(v.z); o.w = f2bf(v.w);
  ((ushort4*)out)[i] = o;
}

// ======================= 256x256 A-direct NT GEMM =======================
// C[m][n] = alpha * sum_k A[m][k]*B[n][k].  8 waves (2M x 4N), BK=64.
// A: NO LDS — per-lane global_load_dwordx4 fragments (16 rows x 64B full lines).
// B: LDS double-buffer 2x32KB, staged one FULL K-tile ahead via global_load_lds
//    (linear dest + inverse-swizzled source; read with elem ^= (row&7)<<3 — 0 conflicts).
// One vmcnt(0)+barrier per K-tile (B staged ~2500 cyc before use -> drain is free).
// LDS traffic per K-tile: 96 KB (vs 256 KB with A staged) — below the MFMA floor.
// MODE 0: fp32 out, blockIdx.z in [0,4) selects K-chunk and (C0..C3, ldc0..3).
// MODE 2: QKV epilogue: cols [0,2048) -> bf16 Cqk; cols [2048,3072) -> vT via
//         LDS-staged transpose (coalesced 16B stores, kills the 8B-scatter).
template <int MODE>
__global__ __launch_bounds__(512, 2) void gemm8(
    const unsigned short* __restrict__ A, int lda,
    const unsigned short* __restrict__ B, int ldb,
    int ksplit, float alpha,
    float* __restrict__ C0, int ldc0, float* __restrict__ C1, int ldc1,
    float* __restrict__ C2, int ldc2, float* __restrict__ C3, int ldc3,
    unsigned short* __restrict__ Cqk, int ldqk,
    unsigned short* __restrict__ CvT, int ldvt) {
  // 68 KB: B buffers at 0 / 16384 (ushorts, 32 KB each); epilogue transpose reuses [0, 34816)
  __shared__ __attribute__((aligned(16))) unsigned short lds[34816];

  const int t    = threadIdx.x;
  const int lane = t & 63;
  const int wave = t >> 6;
  const int wr   = wave >> 2;        // 0..1  (M)
  const int wc   = wave & 3;         // 0..3  (N)

  // XCD-aware bijective swizzle on the xy plane (nwg % 8 == 0 for all our grids)
  const int nx   = gridDim.x;
  const int nwg  = nx * gridDim.y;
  const int orig = blockIdx.y * nx + blockIdx.x;
  const int wg   = (orig & 7) * (nwg >> 3) + (orig >> 3);
  const int bm   = (wg / nx) * 256;
  const int bn   = (wg % nx) * 256;

  const int kbeg = blockIdx.z * ksplit;
  const int NT   = ksplit >> 6;

  const unsigned short* gB = B + (size_t)bn * ldb;

  const int frow  = lane & 15;
  const int fk    = (lane >> 4) * 8;
  const int brow0 = wc * 64;

  // per-lane A fragment base: row = bm + wr*128 + frow (+ mi*16), col = kbeg + fk (+ u*64 + ks*32)
  const unsigned short* Arow = A + (size_t)(bm + wr * 128 + frow) * lda + kbeg + fk;

  // stage the full 256x64 B-tile: linear LDS dest, inverse-swizzled global source
  auto stageB = [&](int k0, unsigned short* dst) {
#pragma unroll
    for (int j = 0; j < 4; ++j) {
      const int de = t * 8 + j * 4096;                 // dest elem (row = de>>6, k = de&63)
      const int se = de ^ (((de >> 6) & 7) << 3);      // pre-swizzled source elem
      __builtin_amdgcn_global_load_lds(
          (const __attribute__((address_space(1))) void*)(gB + (size_t)(se >> 6) * ldb + k0 + (se & 63)),
          (__attribute__((address_space(3))) void*)(dst + de),
          16, 0, 0);
    }
  };

  f32x4 acc[8][4];
#pragma unroll
  for (int i = 0; i < 8; ++i)
#pragma unroll
    for (int j = 0; j < 4; ++j)
      acc[i][j] = (f32x4){0.f, 0.f, 0.f, 0.f};

  // ---- prologue: stage B(0) -> buf0, drain, barrier ----
  stageB(kbeg, lds);
  asm volatile("s_waitcnt vmcnt(0)" ::: "memory");
  __builtin_amdgcn_s_barrier();

  for (int u = 0; u < NT; ++u) {
    const unsigned short* Bc = lds + (u & 1) * 16384;
    unsigned short*       Bn = lds + ((u + 1) & 1) * 16384;
    const unsigned short* Au = Arow + u * 64;

    short8 a0[8], a1[8], b0[4], b1[4];

    // A fragments ks=0 (direct global; compiler-tracked waits)
#pragma unroll
    for (int mi = 0; mi < 8; ++mi)
      a0[mi] = *(const short8*)(Au + (size_t)mi * 16 * lda);
    // B fragments ks=0
#pragma unroll
    for (int n = 0; n < 4; ++n) {
      const int row = brow0 + n * 16 + frow;
      b0[n] = *(const short8*)(Bc + ((row * 64 + fk) ^ ((row & 7) << 3)));
    }
    // A fragments ks=1
#pragma unroll
    for (int mi = 0; mi < 8; ++mi)
      a1[mi] = *(const short8*)(Au + (size_t)mi * 16 * lda + 32);
    // stage B(u+1) one full tile ahead
    if (u + 1 < NT) stageB(kbeg + (u + 1) * 64, Bn);
    // B fragments ks=1
#pragma unroll
    for (int n = 0; n < 4; ++n) {
      const int row = brow0 + n * 16 + frow;
      b1[n] = *(const short8*)(Bc + ((row * 64 + 32 + fk) ^ ((row & 7) << 3)));
    }

    __builtin_amdgcn_s_setprio(1);
#pragma unroll
    for (int mi = 0; mi < 8; ++mi)
#pragma unroll
      for (int n = 0; n < 4; ++n)
        acc[mi][n] = __builtin_amdgcn_mfma_f32_16x16x32_bf16(a0[mi], b0[n], acc[mi][n], 0, 0, 0);
    __builtin_amdgcn_s_setprio(0);
    __builtin_amdgcn_s_setprio(1);
#pragma unroll
    for (int mi = 0; mi < 8; ++mi)
#pragma unroll
      for (int n = 0; n < 4; ++n)
        acc[mi][n] = __builtin_amdgcn_mfma_f32_16x16x32_bf16(a1[mi], b1[n], acc[mi][n], 0, 0, 0);
    __builtin_amdgcn_s_setprio(0);

    asm volatile("s_waitcnt vmcnt(0)" ::: "memory");   // B(u+1) landed (issued ~1 tile ago)
    __builtin_amdgcn_s_barrier();
  }

  // ---- epilogue ----
  if constexpr (MODE == 0) {
#pragma unroll
    for (int m = 0; m < 8; ++m) {
#pragma unroll
      for (int n = 0; n < 4; ++n) {
        const int row0 = bm + wr * 128 + m * 16 + (lane >> 4) * 4;
        const int col  = bn + wc * 64 + n * 16 + (lane & 15);
        float* C; int ldc;
        if      (blockIdx.z == 0) { C = C0; ldc = ldc0; }
        else if (blockIdx.z == 1) { C = C1; ldc = ldc1; }
        else if (blockIdx.z == 2) { C = C2; ldc = ldc2; }
        else                      { C = C3; ldc = ldc3; }
#pragma unroll
        for (int j = 0; j < 4; ++j)
          C[(size_t)(row0 + j) * ldc + col] = acc[m][n][j] * alpha;
      }
    }
  } else {
    if (bn < 2048) {
#pragma unroll
      for (int m = 0; m < 8; ++m) {
#pragma unroll
        for (int n = 0; n < 4; ++n) {
          const int row0 = bm + wr * 128 + m * 16 + (lane >> 4) * 4;
          const int col  = bn + wc * 64 + n * 16 + (lane & 15);
#pragma unroll
          for (int j = 0; j < 4; ++j)
            Cqk[(size_t)(row0 + j) * ldqk + col] = f2bf(acc[m][n][j] * alpha);
        }
      }
    } else {
      // vT via LDS transpose: T[c][r] ushort, stride 136 (16B-align per row, bank-spread)
      // pass p: waves wr==p deposit their 128 rows; all threads copy out coalesced.
#pragma unroll
      for (int p = 0; p < 2; ++p) {
        if (wr == p) {
#pragma unroll
          for (int m = 0; m < 8; ++m) {
#pragma unroll
            for (int n = 0; n < 4; ++n) {
              const int c = wc * 64 + n * 16 + (lane & 15);        // local col (dout)
              const int r = m * 16 + (lane >> 4) * 4;              // local row (seq) within pass
              ushort4 o;
              o.x = f2bf(acc[m][n][0] * alpha);
              o.y = f2bf(acc[m][n][1] * alpha);
              o.z = f2bf(acc[m][n][2] * alpha);
              o.w = f2bf(acc[m][n][3] * alpha);
              *(ushort4*)(lds + c * 136 + r) = o;
            }
          }
        }
        __syncthreads();
        {
          const int c  = t >> 1;                 // 0..255 local dout col
          const int rh = (t & 1) * 64;           // row-half within pass
          const unsigned short* src = lds + c * 136 + rh;
          unsigned short* dst = CvT + (size_t)(bn - 2048 + c) * ldvt + bm + p * 128 + rh;
#pragma unroll
          for (int i = 0; i < 8; ++i)
            *(short8*)(dst + i * 8) = *(const short8*)(src + i * 8);
        }
        __syncthreads();
      }
    }
  }
}

// ---------------- row softmax over S (fp32 [4096][4096]); writes bf16 P in place ----------------
__global__ __launch_bounds__(256) void softmax_rows(float* __restrict__ S) {
  const int row  = blockIdx.x;
  const int t    = threadIdx.x;
  const int lane = t & 63;
  const int wave = t >> 6;

  const float4* src = (const float4*)(S + (size_t)row * 4096);
  float4 v[4];
  float m = -3.0e38f;
#pragma unroll
  for (int i = 0; i < 4; ++i) {
    v[i] = src[t + 256 * i];
    m = fmaxf(m, fmaxf(fmaxf(v[i].x, v[i].y), fmaxf(v[i].z, v[i].w)));
  }
#pragma unroll
  for (int off = 1; off < 64; off <<= 1)
    m = fmaxf(m, __shfl_xor(m, off));

  __shared__ float red[4];
  if (lane == 0) red[wave] = m;
  __syncthreads();
  m = fmaxf(fmaxf(red[0], red[1]), fmaxf(red[2], red[3]));
  __syncthreads();

  float p[16];
  float s = 0.f;
#pragma unroll
  for (int i = 0; i < 4; ++i) {
    p[4 * i + 0] = __expf(v[i].x - m);
    p[4 * i + 1] = __expf(v[i].y - m);
    p[4 * i + 2] = __expf(v[i].z - m);
    p[4 * i + 3] = __expf(v[i].w - m);
    s += p[4 * i + 0] + p[4 * i + 1] + p[4 * i + 2] + p[4 * i + 3];
  }
#pragma unroll
  for (int off = 1; off < 64; off <<= 1)
    s += __shfl_xor(s, off);
  if (lane == 0) red[wave] = s;
  __syncthreads();
  s = red[0] + red[1] + red[2] + red[3];
  const float inv = 1.0f / s;

  unsigned short* dst = (unsigned short*)S + (size_t)row * 8192;
#pragma unroll
  for (int i = 0; i < 4; ++i) {
    ushort4 o;
    o.x = f2bf(p[4 * i + 0] * inv);
    o.y = f2bf(p[4 * i + 1] * inv);
    o.z = f2bf(p[4 * i + 2] * inv);
    o.w = f2bf(p[4 * i + 3] * inv);
    *(ushort4*)(dst + 4 * (t + 256 * i)) = o;
  }
}

// ---------------- combine split-K=4 partials: out += p1 + p2 + p3 ----------------
// out/p1: ld 1024; p2/p3: ld 4096 floats (live in the odd 8KB halves of S rows)
__global__ __launch_bounds__(256) void combine4(float* __restrict__ out,
                                                const float* __restrict__ p1,
                                                const float* __restrict__ p2,
                                                const float* __restrict__ p3) {
  const int r = blockIdx.x, c = threadIdx.x;
  float4 o = ((float4*)(out + (size_t)r * 1024))[c];
  float4 a = ((const float4*)(p1 + (size_t)r * 1024))[c];
  float4 b = ((const float4*)(p2 + (size_t)r * 4096))[c];
  float4 d = ((const float4*)(p3 + (size_t)r * 4096))[c];
  o.x += a.x + b.x + d.x;
  o.y += a.y + b.y + d.y;
  o.z += a.z + b.z + d.z;
  o.w += a.w + b.w + d.w;
  ((float4*)(out + (size_t)r * 1024))[c] = o;
}

// ---------------- launch ----------------
extern "C" void kernel_launch(void* const* d_in, const int* in_sizes, int n_in,
                              void* d_out, int out_size, void* d_ws, size_t ws_size,
                              hipStream_t stream) {
  const float* x  = (const float*)d_in[0];
  const float* Wq = (const float*)d_in[1];
  const float* Wk = (const float*)d_in[2];
  const float* Wv = (const float*)d_in[3];

  // ws layout (bytes):
  //   [0, 64M)   : S fp32 [4096][4096]; after softmax row r holds: P bf16 at [r*16K, r*16K+8K),
  //                ctx partial z=2 at [+8K,+12K), z=3 at [+12K,+16K)
  //   [64M, 80M) : QK bf16 [4096][2048] (q|k); dead after scores -> ctx partial z=1 fp32
  //   [80M, 88M) : vT bf16 [1024][4096]
  //   [88M, 96M) : xb bf16 [4096][1024]
  //   [96M,102M) : Wcat bf16 [3072][1024]
  char* ws = (char*)d_ws;
  float*          S     = (float*)ws;
  unsigned short* Pm    = (unsigned short*)ws;                // bf16 view, row stride 8192
  float*          Cp2   = (float*)(ws + 8192);                // ld 4096
  float*          Cp3   = (float*)(ws + 12288);               // ld 4096
  unsigned short* QK    = (unsigned short*)(ws + 67108864);
  float*          Cp1   = (float*)(ws + 67108864);            // ld 1024 (reuse after scores)
  unsigned short* vT    = (unsigned short*)(ws + 83886080);   // [1024][4096]
  unsigned short* xb    = (unsigned short*)(ws + 92274688);
  unsigned short* Wcat  = (unsigned short*)(ws + 100663296);

  cast_kernel<<<4096, 256, 0, stream>>>(x,  xb,            1048576);
  cast_kernel<<<1024, 256, 0, stream>>>(Wq, Wcat,           262144);
  cast_kernel<<<1024, 256, 0, stream>>>(Wk, Wcat + 1048576, 262144);
  cast_kernel<<<1024, 256, 0, stream>>>(Wv, Wcat + 2097152, 262144);

  // fused QKV: [4096][3072] = xb @ Wcat^T; q|k -> QK bf16, v -> vT (LDS-transposed store)
  gemm8<2><<<dim3(12, 16, 1), 512, 0, stream>>>(
      xb, 1024, Wcat, 1024, 1024, 1.0f,
      nullptr, 0, nullptr, 0, nullptr, 0, nullptr, 0, QK, 2048, vT, 4096);

  // S = (q @ k^T) / 32  (fp32)
  gemm8<0><<<dim3(16, 16, 1), 512, 0, stream>>>(
      QK, 2048, QK + 1024, 2048, 1024, 0.03125f,
      S, 4096, nullptr, 0, nullptr, 0, nullptr, 0, nullptr, 0, nullptr, 0);

  softmax_rows<<<4096, 256, 0, stream>>>(S);

  // context = P @ vT^T, split-K=4; z=0 -> d_out, z=1..3 -> partials; then combine
  gemm8<0><<<dim3(4, 16, 4), 512, 0, stream>>>(
      Pm, 8192, vT, 4096, 1024, 1.0f,
      (float*)d_out, 1024, Cp1, 1024, Cp2, 4096, Cp3, 4096, nullptr, 0, nullptr, 0);
  combine4<<<4096, 256, 0, stream>>>((float*)d_out, Cp1, Cp2, Cp3);
}

// Round 8
// 163.134 us; speedup vs baseline: 1.8394x; 1.8394x over previous
//
#include <hip/hip_runtime.h>

typedef __attribute__((ext_vector_type(4))) float f32x4;
typedef __attribute__((ext_vector_type(8))) short short8;
typedef _Float16 half8 __attribute__((ext_vector_type(8)));

__device__ __forceinline__ unsigned short f2h(float f) {
  _Float16 h = (_Float16)f;                       // RTN
  return __builtin_bit_cast(unsigned short, h);
}
__device__ __forceinline__ float h2f(unsigned short u) {
  return (float)__builtin_bit_cast(_Float16, u);
}

// ---------------- cast fp32 -> fp16 (stored as ushort), 4 elems/thread ----------------
__global__ __launch_bounds__(256) void cast_kernel(const float* __restrict__ in,
                                                   unsigned short* __restrict__ out,
                                                   int n4) {
  int i = blockIdx.x * 256 + threadIdx.x;
  if (i >= n4) return;
  float4 v = ((const float4*)in)[i];
  ushort4 o;
  o.x = f2h(v.x); o.y = f2h(v.y); o.z = f2h(v.z); o.w = f2h(v.w);
  ((ushort4*)out)[i] = o;
}

// ======================= 256x256 8-phase NT GEMM (fp16) =======================
// C[m][n] = alpha * sum_k A[m][k]*B[n][k].  8 waves (2M x 4N), BK=64, 128KB LDS dbuf.
// LDS swizzle: elem ^= (row&7)<<3 — conflict-free b128 column reads (0 conflicts, r4).
// Linear global_load_lds dest + inverse-swizzled global source (same involution).
// MODE 0: fp32 out, blockIdx.z in [0,4) selects K-chunk and (C0..C3, ldc0..3)  [ctx]
// MODE 1: fp16 out to Cqk/ldqk                                                 [scores]
// MODE 2: QKV epilogue: cols [0,2048) -> fp16 Cqk; cols [2048,3072) -> transposed CvT.

#define PHASE(M0, STAGE, TAILWAIT)                                            \
  {                                                                           \
    _Pragma("unroll")                                                         \
    for (int mi = 0; mi < 2; ++mi) {                                          \
      _Pragma("unroll")                                                       \
      for (int ks = 0; ks < 2; ++ks) {                                        \
        const int row = (M0 + mi) * 16 + frow;                                \
        const int e = (row * 64 + ks * 32 + fk) ^ ((row & 7) << 3);           \
        af[mi][ks] = *(const half8*)(const void*)(Acur + e);                  \
      }                                                                       \
    }                                                                         \
    STAGE;                                                                    \
    __builtin_amdgcn_s_barrier();                                             \
    __builtin_amdgcn_s_setprio(1);                                            \
    _Pragma("unroll")                                                         \
    for (int mi = 0; mi < 2; ++mi)                                            \
      _Pragma("unroll")                                                       \
      for (int n = 0; n < 4; ++n)                                             \
        _Pragma("unroll")                                                     \
        for (int ks = 0; ks < 2; ++ks)                                        \
          acc[M0 + mi][n] = __builtin_amdgcn_mfma_f32_16x16x32_f16(           \
              af[mi][ks], bf[n][ks], acc[M0 + mi][n], 0, 0, 0);               \
    __builtin_amdgcn_s_setprio(0);                                            \
    TAILWAIT;                                                                 \
    __builtin_amdgcn_s_barrier();                                             \
  }

template <int MODE>
__global__ __launch_bounds__(512, 2) void gemm8(
    const unsigned short* __restrict__ A, int lda,
    const unsigned short* __restrict__ B, int ldb,
    int ksplit, float alpha,
    float* __restrict__ C0, int ldc0, float* __restrict__ C1, int ldc1,
    float* __restrict__ C2, int ldc2, float* __restrict__ C3, int ldc3,
    unsigned short* __restrict__ Cqk, int ldqk,
    unsigned short* __restrict__ CvT, int ldvt) {
  // 128 KB: buf b at b*32768 (ushorts); A halves at +0,+8192; B halves at +16384,+24576
  __shared__ __attribute__((aligned(16))) unsigned short lds[65536];

  const int t    = threadIdx.x;
  const int lane = t & 63;
  const int wave = t >> 6;
  const int wr   = wave >> 2;        // 0..1  (M)
  const int wc   = wave & 3;         // 0..3  (N)

  // XCD-aware bijective swizzle on the xy plane (nwg % 8 == 0 for all our grids)
  const int nx   = gridDim.x;
  const int nwg  = nx * gridDim.y;
  const int orig = blockIdx.y * nx + blockIdx.x;
  const int wg   = (orig & 7) * (nwg >> 3) + (orig >> 3);
  const int bm   = (wg / nx) * 256;
  const int bn   = (wg % nx) * 256;

  const int kbeg = blockIdx.z * ksplit;
  const int NT   = ksplit >> 6;

  const unsigned short* gA = A + (size_t)bm * lda;
  const unsigned short* gB = B + (size_t)bn * ldb;

  // stage one 128x64 half-tile: linear LDS dest (t*16B + j*8KB), inverse-swizzled source
  auto stage = [&](const unsigned short* gbase, int ld, int k0, unsigned short* dst) {
#pragma unroll
    for (int j = 0; j < 2; ++j) {
      const int de = t * 8 + j * 4096;                 // dest elem within half (linear)
      const int se = de ^ (((de >> 6) & 7) << 3);      // pre-swizzled source elem
      __builtin_amdgcn_global_load_lds(
          (const __attribute__((address_space(1))) void*)(gbase + (size_t)(se >> 6) * ld + k0 + (se & 63)),
          (__attribute__((address_space(3))) void*)(dst + de),
          16, 0, 0);
    }
  };

  f32x4 acc[8][4];
#pragma unroll
  for (int i = 0; i < 8; ++i)
#pragma unroll
    for (int j = 0; j < 4; ++j)
      acc[i][j] = (f32x4){0.f, 0.f, 0.f, 0.f};

  const int frow = lane & 15;
  const int fk   = (lane >> 4) * 8;

  // ---- prologue: K-tile 0 (A0,A1,B0,B1) + K-tile 1's B halves; leave B(1) in flight ----
  stage(gA,                     lda, kbeg, lds);
  stage(gA + (size_t)128 * lda, lda, kbeg, lds + 8192);
  stage(gB,                     ldb, kbeg, lds + 16384);
  stage(gB + (size_t)128 * ldb, ldb, kbeg, lds + 24576);
  if (NT > 1) {
    stage(gB,                     ldb, kbeg + 64, lds + 32768 + 16384);
    stage(gB + (size_t)128 * ldb, ldb, kbeg + 64, lds + 32768 + 24576);
    asm volatile("s_waitcnt vmcnt(4)" ::: "memory");
  } else {
    asm volatile("s_waitcnt vmcnt(0)" ::: "memory");
  }
  __builtin_amdgcn_s_barrier();

  for (int u = 0; u < NT; ++u) {
    const int cur = u & 1, nxt = cur ^ 1;
    const unsigned short* Acur = lds + cur * 32768 + wr * 8192;
    const unsigned short* Bcur = lds + cur * 32768 + 16384 + (wc >> 1) * 8192;
    const int brow0 = (wc & 1) * 64;

    half8 bf[4][2];
    half8 af[2][2];

    // B fragments for the whole K-tile (read once, phase 0)
#pragma unroll
    for (int n = 0; n < 4; ++n)
#pragma unroll
      for (int ks = 0; ks < 2; ++ks) {
        const int row = brow0 + n * 16 + frow;
        const int e = (row * 64 + ks * 32 + fk) ^ ((row & 7) << 3);
        bf[n][ks] = *(const half8*)(const void*)(Bcur + e);
      }

    // ph0: A m{0,1}; stage A-half0(u+1) -> other buf
    PHASE(0,
          if (u + 1 < NT) stage(gA, lda, kbeg + (u + 1) * 64, lds + nxt * 32768),
          );
    // ph1: A m{2,3}; stage A-half1(u+1)
    PHASE(2,
          if (u + 1 < NT) stage(gA + (size_t)128 * lda, lda, kbeg + (u + 1) * 64, lds + nxt * 32768 + 8192),
          );
    // ph2: A m{4,5}; stage B-half0(u+2) -> cur buf (B dead since ph0)
    PHASE(4,
          if (u + 2 < NT) stage(gB, ldb, kbeg + (u + 2) * 64, lds + cur * 32768 + 16384),
          );
    // ph3: A m{6,7}; stage B-half1(u+2); counted vmcnt at K-tile boundary
    PHASE(6,
          if (u + 2 < NT) stage(gB + (size_t)128 * ldb, ldb, kbeg + (u + 2) * 64, lds + cur * 32768 + 24576),
          if (u + 2 < NT) { asm volatile("s_waitcnt vmcnt(4)" ::: "memory"); }
          else            { asm volatile("s_waitcnt vmcnt(0)" ::: "memory"); } );
  }

  // ---- epilogue ----
#pragma unroll
  for (int m = 0; m < 8; ++m) {
#pragma unroll
    for (int n = 0; n < 4; ++n) {
      const int row0 = bm + wr * 128 + m * 16 + (lane >> 4) * 4;
      const int col  = bn + wc * 64 + n * 16 + (lane & 15);
      if constexpr (MODE == 0) {
        float* C; int ldc;
        if      (blockIdx.z == 0) { C = C0; ldc = ldc0; }
        else if (blockIdx.z == 1) { C = C1; ldc = ldc1; }
        else if (blockIdx.z == 2) { C = C2; ldc = ldc2; }
        else                      { C = C3; ldc = ldc3; }
#pragma unroll
        for (int j = 0; j < 4; ++j)
          C[(size_t)(row0 + j) * ldc + col] = acc[m][n][j] * alpha;
      } else if constexpr (MODE == 1) {
#pragma unroll
        for (int j = 0; j < 4; ++j)
          Cqk[(size_t)(row0 + j) * ldqk + col] = f2h(acc[m][n][j] * alpha);
      } else {
        if (bn < 2048) {
#pragma unroll
          for (int j = 0; j < 4; ++j)
            Cqk[(size_t)(row0 + j) * ldqk + col] = f2h(acc[m][n][j] * alpha);
        } else {
          ushort4 o;
          o.x = f2h(acc[m][n][0] * alpha);
          o.y = f2h(acc[m][n][1] * alpha);
          o.z = f2h(acc[m][n][2] * alpha);
          o.w = f2h(acc[m][n][3] * alpha);
          *(ushort4*)(CvT + (size_t)(col - 2048) * ldvt + row0) = o;
        }
      }
    }
  }
}

// ---------------- row softmax over fp16 S rows (stride 8192 ushorts); in-place ----------------
// P written pre-scaled by 512 (ctx GEMM uses alpha = 1/512) to stay out of fp16 subnormals.
__global__ __launch_bounds__(256) void softmax_rows(unsigned short* __restrict__ S) {
  const int row  = blockIdx.x;
  const int t    = threadIdx.x;
  const int lane = t & 63;
  const int wave = t >> 6;

  unsigned short* base = S + (size_t)row * 8192;
  ushort4 v[4];  // 16 halves/thread, contiguous 32B at t*16
  float f[16];
  float m = -3.0e38f;
#pragma unroll
  for (int i = 0; i < 4; ++i) {
    v[i] = ((const ushort4*)(base + t * 16))[i];
    f[4 * i + 0] = h2f(v[i].x);
    f[4 * i + 1] = h2f(v[i].y);
    f[4 * i + 2] = h2f(v[i].z);
    f[4 * i + 3] = h2f(v[i].w);
    m = fmaxf(m, fmaxf(fmaxf(f[4 * i + 0], f[4 * i + 1]), fmaxf(f[4 * i + 2], f[4 * i + 3])));
  }
#pragma unroll
  for (int off = 1; off < 64; off <<= 1)
    m = fmaxf(m, __shfl_xor(m, off));

  __shared__ float red[4];
  if (lane == 0) red[wave] = m;
  __syncthreads();
  m = fmaxf(fmaxf(red[0], red[1]), fmaxf(red[2], red[3]));
  __syncthreads();

  float s = 0.f;
#pragma unroll
  for (int i = 0; i < 16; ++i) {
    f[i] = __expf(f[i] - m);
    s += f[i];
  }
#pragma unroll
  for (int off = 1; off < 64; off <<= 1)
    s += __shfl_xor(s, off);
  if (lane == 0) red[wave] = s;
  __syncthreads();
  s = red[0] + red[1] + red[2] + red[3];
  const float inv = 512.0f / s;

#pragma unroll
  for (int i = 0; i < 4; ++i) {
    ushort4 o;
    o.x = f2h(f[4 * i + 0] * inv);
    o.y = f2h(f[4 * i + 1] * inv);
    o.z = f2h(f[4 * i + 2] * inv);
    o.w = f2h(f[4 * i + 3] * inv);
    ((ushort4*)(base + t * 16))[i] = o;
  }
}

// ---------------- combine split-K=4 partials: out += p1 + p2 + p3 ----------------
// out/p1: ld 1024; p2/p3: ld 4096 floats (live in the odd 8KB halves of S rows)
__global__ __launch_bounds__(256) void combine4(float* __restrict__ out,
                                                const float* __restrict__ p1,
                                                const float* __restrict__ p2,
                                                const float* __restrict__ p3) {
  const int r = blockIdx.x, c = threadIdx.x;
  float4 o = ((float4*)(out + (size_t)r * 1024))[c];
  float4 a = ((const float4*)(p1 + (size_t)r * 1024))[c];
  float4 b = ((const float4*)(p2 + (size_t)r * 4096))[c];
  float4 d = ((const float4*)(p3 + (size_t)r * 4096))[c];
  o.x += a.x + b.x + d.x;
  o.y += a.y + b.y + d.y;
  o.z += a.z + b.z + d.z;
  o.w += a.w + b.w + d.w;
  ((float4*)(out + (size_t)r * 1024))[c] = o;
}

// ---------------- launch ----------------
extern "C" void kernel_launch(void* const* d_in, const int* in_sizes, int n_in,
                              void* d_out, int out_size, void* d_ws, size_t ws_size,
                              hipStream_t stream) {
  const float* x  = (const float*)d_in[0];
  const float* Wq = (const float*)d_in[1];
  const float* Wk = (const float*)d_in[2];
  const float* Wv = (const float*)d_in[3];

  // ws layout (bytes) — identical footprint to round 4:
  //   [0, 64M)   : S/P fp16, row r at [r*16K, r*16K+8K) (stride 8192 ushorts);
  //                ctx partial z=2 fp32 at [+8K,+12K), z=3 at [+12K,+16K)
  //   [64M, 80M) : QK fp16 [4096][2048] (q|k); dead after scores -> ctx partial z=1 fp32
  //   [80M, 88M) : vT fp16 [1024][4096]
  //   [88M, 96M) : xb fp16 [4096][1024]
  //   [96M,102M) : Wcat fp16 [3072][1024]
  char* ws = (char*)d_ws;
  unsigned short* Sh    = (unsigned short*)ws;                // fp16 S/P, row stride 8192
  float*          Cp2   = (float*)(ws + 8192);                // ld 4096
  float*          Cp3   = (float*)(ws + 12288);               // ld 4096
  unsigned short* QK    = (unsigned short*)(ws + 67108864);
  float*          Cp1   = (float*)(ws + 67108864);            // ld 1024 (reuse after scores)
  unsigned short* vT    = (unsigned short*)(ws + 83886080);   // [1024][4096]
  unsigned short* xb    = (unsigned short*)(ws + 92274688);
  unsigned short* Wcat  = (unsigned short*)(ws + 100663296);

  cast_kernel<<<4096, 256, 0, stream>>>(x,  xb,            1048576);
  cast_kernel<<<1024, 256, 0, stream>>>(Wq, Wcat,           262144);
  cast_kernel<<<1024, 256, 0, stream>>>(Wk, Wcat + 1048576, 262144);
  cast_kernel<<<1024, 256, 0, stream>>>(Wv, Wcat + 2097152, 262144);

  // fused QKV: [4096][3072] = xb @ Wcat^T; q|k -> QK fp16, v -> vT (transposed)
  gemm8<2><<<dim3(12, 16, 1), 512, 0, stream>>>(
      xb, 1024, Wcat, 1024, 1024, 1.0f,
      nullptr, 0, nullptr, 0, nullptr, 0, nullptr, 0, QK, 2048, vT, 4096);

  // S = (q @ k^T) / 32  (fp16 out, row stride 8192)
  gemm8<1><<<dim3(16, 16, 1), 512, 0, stream>>>(
      QK, 2048, QK + 1024, 2048, 1024, 0.03125f,
      nullptr, 0, nullptr, 0, nullptr, 0, nullptr, 0, Sh, 8192, nullptr, 0);

  softmax_rows<<<4096, 256, 0, stream>>>(Sh);

  // context = (P/512) @ vT^T * ... alpha=1/512 undoes softmax pre-scale; split-K=4
  gemm8<0><<<dim3(4, 16, 4), 512, 0, stream>>>(
      Sh, 8192, vT, 4096, 1024, 1.0f / 512.0f,
      (float*)d_out, 1024, Cp1, 1024, Cp2, 4096, Cp3, 4096, nullptr, 0, nullptr, 0);
  combine4<<<4096, 256, 0, stream>>>((float*)d_out, Cp1, Cp2, Cp3);
}

// Round 10
// 154.422 us; speedup vs baseline: 1.9432x; 1.0564x over previous
//
#include <hip/hip_runtime.h>

typedef __attribute__((ext_vector_type(4))) float f32x4;
typedef __attribute__((ext_vector_type(8))) short short8;
typedef _Float16 half8 __attribute__((ext_vector_type(8)));

__device__ __forceinline__ unsigned short f2h(float f) {
  _Float16 h = (_Float16)f;                       // RTN
  return __builtin_bit_cast(unsigned short, h);
}
__device__ __forceinline__ float h2f(unsigned short u) {
  return (float)__builtin_bit_cast(_Float16, u);
}

// ---------------- cast fp32 -> fp16 (stored as ushort), 4 elems/thread ----------------
__global__ __launch_bounds__(256) void cast_kernel(const float* __restrict__ in,
                                                   unsigned short* __restrict__ out,
                                                   int n4) {
  int i = blockIdx.x * 256 + threadIdx.x;
  if (i >= n4) return;
  float4 v = ((const float4*)in)[i];
  ushort4 o;
  o.x = f2h(v.x); o.y = f2h(v.y); o.z = f2h(v.z); o.w = f2h(v.w);
  ((ushort4*)out)[i] = o;
}

// ---------------- cast 3 weight matrices into contiguous Wcat (one launch) ----------------
// Each W is 1024x1024 fp32 = 1048576 elems; segment s of Wcat starts at s*1048576 ushorts.
__global__ __launch_bounds__(256) void cast3_kernel(const float* __restrict__ w0,
                                                    const float* __restrict__ w1,
                                                    const float* __restrict__ w2,
                                                    unsigned short* __restrict__ out) {
  const int b = blockIdx.x;                  // 0..3071; 1024 blocks per segment
  const int seg = b >> 10;
  const float* src = (seg == 0) ? w0 : (seg == 1) ? w1 : w2;
  const int i = (b & 1023) * 256 + threadIdx.x;       // float4 index, < 262144 per segment
  float4 v = ((const float4*)src)[i];
  ushort4 o;
  o.x = f2h(v.x); o.y = f2h(v.y); o.z = f2h(v.z); o.w = f2h(v.w);
  ((ushort4*)(out + (size_t)seg * 1048576))[i] = o;   // seg stride = 1048576 ushorts
}

// ======================= 256x256 8-phase NT GEMM (fp16) =======================
// C[m][n] = alpha * sum_k A[m][k]*B[n][k].  8 waves (2M x 4N), BK=64, 128KB LDS dbuf.
// LDS swizzle: elem ^= (row&7)<<3 — conflict-free b128 column reads (0 conflicts, r4).
// Linear global_load_lds dest + inverse-swizzled global source (same involution).
// MFMA order: ks OUTER -> consecutive MFMAs touch distinct acc registers (dep dist 8).
// MODE 0: blockIdx.z in [0,4): z=0 -> fp32 C0/ldc0, z=1..3 -> fp16 H1..H3/ldh  [ctx]
// MODE 1: fp16 out to Cqk/ldqk                                                 [scores]
// MODE 2: QKV epilogue: cols [0,2048) -> fp16 Cqk; cols [2048,3072) -> transposed CvT.

#define PHASE(M0, STAGE, TAILWAIT)                                            \
  {                                                                           \
    _Pragma("unroll")                                                         \
    for (int mi = 0; mi < 2; ++mi) {                                          \
      _Pragma("unroll")                                                       \
      for (int ks = 0; ks < 2; ++ks) {                                        \
        const int row = (M0 + mi) * 16 + frow;                                \
        const int e = (row * 64 + ks * 32 + fk) ^ ((row & 7) << 3);           \
        af[mi][ks] = *(const half8*)(const void*)(Acur + e);                  \
      }                                                                       \
    }                                                                         \
    STAGE;                                                                    \
    __builtin_amdgcn_s_barrier();                                             \
    __builtin_amdgcn_s_setprio(1);                                            \
    _Pragma("unroll")                                                         \
    for (int ks = 0; ks < 2; ++ks)                                            \
      _Pragma("unroll")                                                       \
      for (int mi = 0; mi < 2; ++mi)                                          \
        _Pragma("unroll")                                                     \
        for (int n = 0; n < 4; ++n)                                           \
          acc[M0 + mi][n] = __builtin_amdgcn_mfma_f32_16x16x32_f16(           \
              af[mi][ks], bf[n][ks], acc[M0 + mi][n], 0, 0, 0);               \
    __builtin_amdgcn_s_setprio(0);                                            \
    TAILWAIT;                                                                 \
    __builtin_amdgcn_s_barrier();                                             \
  }

template <int MODE>
__global__ __launch_bounds__(512, 2) void gemm8(
    const unsigned short* __restrict__ A, int lda,
    const unsigned short* __restrict__ B, int ldb,
    int ksplit, float alpha,
    float* __restrict__ C0, int ldc0,
    unsigned short* __restrict__ H1, int ldh1,
    unsigned short* __restrict__ H2, int ldh2,
    unsigned short* __restrict__ H3, int ldh3,
    unsigned short* __restrict__ Cqk, int ldqk,
    unsigned short* __restrict__ CvT, int ldvt) {
  // 128 KB: buf b at b*32768 (ushorts); A halves at +0,+8192; B halves at +16384,+24576
  __shared__ __attribute__((aligned(16))) unsigned short lds[65536];

  const int t    = threadIdx.x;
  const int lane = t & 63;
  const int wave = t >> 6;
  const int wr   = wave >> 2;        // 0..1  (M)
  const int wc   = wave & 3;         // 0..3  (N)

  // XCD-aware bijective swizzle on the xy plane (nwg % 8 == 0 for all our grids)
  const int nx   = gridDim.x;
  const int nwg  = nx * gridDim.y;
  const int orig = blockIdx.y * nx + blockIdx.x;
  const int wg   = (orig & 7) * (nwg >> 3) + (orig >> 3);
  const int bm   = (wg / nx) * 256;
  const int bn   = (wg % nx) * 256;

  const int kbeg = blockIdx.z * ksplit;
  const int NT   = ksplit >> 6;

  const unsigned short* gA = A + (size_t)bm * lda;
  const unsigned short* gB = B + (size_t)bn * ldb;

  // stage one 128x64 half-tile: linear LDS dest (t*16B + j*8KB), inverse-swizzled source
  auto stage = [&](const unsigned short* gbase, int ld, int k0, unsigned short* dst) {
#pragma unroll
    for (int j = 0; j < 2; ++j) {
      const int de = t * 8 + j * 4096;                 // dest elem within half (linear)
      const int se = de ^ (((de >> 6) & 7) << 3);      // pre-swizzled source elem
      __builtin_amdgcn_global_load_lds(
          (const __attribute__((address_space(1))) void*)(gbase + (size_t)(se >> 6) * ld + k0 + (se & 63)),
          (__attribute__((address_space(3))) void*)(dst + de),
          16, 0, 0);
    }
  };

  f32x4 acc[8][4];
#pragma unroll
  for (int i = 0; i < 8; ++i)
#pragma unroll
    for (int j = 0; j < 4; ++j)
      acc[i][j] = (f32x4){0.f, 0.f, 0.f, 0.f};

  const int frow = lane & 15;
  const int fk   = (lane >> 4) * 8;

  // ---- prologue: K-tile 0 (A0,A1,B0,B1) + K-tile 1's B halves; leave B(1) in flight ----
  stage(gA,                     lda, kbeg, lds);
  stage(gA + (size_t)128 * lda, lda, kbeg, lds + 8192);
  stage(gB,                     ldb, kbeg, lds + 16384);
  stage(gB + (size_t)128 * ldb, ldb, kbeg, lds + 24576);
  if (NT > 1) {
    stage(gB,                     ldb, kbeg + 64, lds + 32768 + 16384);
    stage(gB + (size_t)128 * ldb, ldb, kbeg + 64, lds + 32768 + 24576);
    asm volatile("s_waitcnt vmcnt(4)" ::: "memory");
  } else {
    asm volatile("s_waitcnt vmcnt(0)" ::: "memory");
  }
  __builtin_amdgcn_s_barrier();

  for (int u = 0; u < NT; ++u) {
    const int cur = u & 1, nxt = cur ^ 1;
    const unsigned short* Acur = lds + cur * 32768 + wr * 8192;
    const unsigned short* Bcur = lds + cur * 32768 + 16384 + (wc >> 1) * 8192;
    const int brow0 = (wc & 1) * 64;

    half8 bf[4][2];
    half8 af[2][2];

    // B fragments for the whole K-tile (read once, phase 0)
#pragma unroll
    for (int n = 0; n < 4; ++n)
#pragma unroll
      for (int ks = 0; ks < 2; ++ks) {
        const int row = brow0 + n * 16 + frow;
        const int e = (row * 64 + ks * 32 + fk) ^ ((row & 7) << 3);
        bf[n][ks] = *(const half8*)(const void*)(Bcur + e);
      }

    // ph0: A m{0,1}; stage A-half0(u+1) -> other buf
    PHASE(0,
          if (u + 1 < NT) stage(gA, lda, kbeg + (u + 1) * 64, lds + nxt * 32768),
          );
    // ph1: A m{2,3}; stage A-half1(u+1)
    PHASE(2,
          if (u + 1 < NT) stage(gA + (size_t)128 * lda, lda, kbeg + (u + 1) * 64, lds + nxt * 32768 + 8192),
          );
    // ph2: A m{4,5}; stage B-half0(u+2) -> cur buf (B dead since ph0)
    PHASE(4,
          if (u + 2 < NT) stage(gB, ldb, kbeg + (u + 2) * 64, lds + cur * 32768 + 16384),
          );
    // ph3: A m{6,7}; stage B-half1(u+2); counted vmcnt at K-tile boundary
    PHASE(6,
          if (u + 2 < NT) stage(gB + (size_t)128 * ldb, ldb, kbeg + (u + 2) * 64, lds + cur * 32768 + 24576),
          if (u + 2 < NT) { asm volatile("s_waitcnt vmcnt(4)" ::: "memory"); }
          else            { asm volatile("s_waitcnt vmcnt(0)" ::: "memory"); } );
  }

  // ---- epilogue ----
#pragma unroll
  for (int m = 0; m < 8; ++m) {
#pragma unroll
    for (int n = 0; n < 4; ++n) {
      const int row0 = bm + wr * 128 + m * 16 + (lane >> 4) * 4;
      const int col  = bn + wc * 64 + n * 16 + (lane & 15);
      if constexpr (MODE == 0) {
        if (blockIdx.z == 0) {
#pragma unroll
          for (int j = 0; j < 4; ++j)
            C0[(size_t)(row0 + j) * ldc0 + col] = acc[m][n][j] * alpha;
        } else {
          unsigned short* H; int ldh;
          if      (blockIdx.z == 1) { H = H1; ldh = ldh1; }
          else if (blockIdx.z == 2) { H = H2; ldh = ldh2; }
          else                      { H = H3; ldh = ldh3; }
#pragma unroll
          for (int j = 0; j < 4; ++j)
            H[(size_t)(row0 + j) * ldh + col] = f2h(acc[m][n][j] * alpha);
        }
      } else if constexpr (MODE == 1) {
#pragma unroll
        for (int j = 0; j < 4; ++j)
          Cqk[(size_t)(row0 + j) * ldqk + col] = f2h(acc[m][n][j] * alpha);
      } else {
        if (bn < 2048) {
#pragma unroll
          for (int j = 0; j < 4; ++j)
            Cqk[(size_t)(row0 + j) * ldqk + col] = f2h(acc[m][n][j] * alpha);
        } else {
          ushort4 o;
          o.x = f2h(acc[m][n][0] * alpha);
          o.y = f2h(acc[m][n][1] * alpha);
          o.z = f2h(acc[m][n][2] * alpha);
          o.w = f2h(acc[m][n][3] * alpha);
          *(ushort4*)(CvT + (size_t)(col - 2048) * ldvt + row0) = o;
        }
      }
    }
  }
}

// ---------------- row softmax over fp16 S rows (stride 8192 ushorts); in-place ----------------
// P written pre-scaled by 512 (ctx GEMM uses alpha = 1/512) to stay out of fp16 subnormals.
__global__ __launch_bounds__(256) void softmax_rows(unsigned short* __restrict__ S) {
  const int row  = blockIdx.x;
  const int t    = threadIdx.x;
  const int lane = t & 63;
  const int wave = t >> 6;

  unsigned short* base = S + (size_t)row * 8192;
  ushort4 v[4];  // 16 halves/thread, contiguous 32B at t*16
  float f[16];
  float m = -3.0e38f;
#pragma unroll
  for (int i = 0; i < 4; ++i) {
    v[i] = ((const ushort4*)(base + t * 16))[i];
    f[4 * i + 0] = h2f(v[i].x);
    f[4 * i + 1] = h2f(v[i].y);
    f[4 * i + 2] = h2f(v[i].z);
    f[4 * i + 3] = h2f(v[i].w);
    m = fmaxf(m, fmaxf(fmaxf(f[4 * i + 0], f[4 * i + 1]), fmaxf(f[4 * i + 2], f[4 * i + 3])));
  }
#pragma unroll
  for (int off = 1; off < 64; off <<= 1)
    m = fmaxf(m, __shfl_xor(m, off));

  __shared__ float red[4];
  if (lane == 0) red[wave] = m;
  __syncthreads();
  m = fmaxf(fmaxf(red[0], red[1]), fmaxf(red[2], red[3]));
  __syncthreads();

  float s = 0.f;
#pragma unroll
  for (int i = 0; i < 16; ++i) {
    f[i] = __expf(f[i] - m);
    s += f[i];
  }
#pragma unroll
  for (int off = 1; off < 64; off <<= 1)
    s += __shfl_xor(s, off);
  if (lane == 0) red[wave] = s;
  __syncthreads();
  s = red[0] + red[1] + red[2] + red[3];
  const float inv = 512.0f / s;

#pragma unroll
  for (int i = 0; i < 4; ++i) {
    ushort4 o;
    o.x = f2h(f[4 * i + 0] * inv);
    o.y = f2h(f[4 * i + 1] * inv);
    o.z = f2h(f[4 * i + 2] * inv);
    o.w = f2h(f[4 * i + 3] * inv);
    ((ushort4*)(base + t * 16))[i] = o;
  }
}

// ---------------- combine split-K=4 partials: out += h2f(p1)+h2f(p2)+h2f(p3) ----------------
// out fp32 ld 1024; p1 fp16 ld 1024; p2/p3 fp16 ld 8192 (odd halves of S rows)
__global__ __launch_bounds__(256) void combine4(float* __restrict__ out,
                                                const unsigned short* __restrict__ p1,
                                                const unsigned short* __restrict__ p2,
                                                const unsigned short* __restrict__ p3) {
  const int r = blockIdx.x, c = threadIdx.x;
  float4 o = ((float4*)(out + (size_t)r * 1024))[c];
  ushort4 a = ((const ushort4*)(p1 + (size_t)r * 1024))[c];
  ushort4 b = ((const ushort4*)(p2 + (size_t)r * 8192))[c];
  ushort4 d = ((const ushort4*)(p3 + (size_t)r * 8192))[c];
  o.x += h2f(a.x) + h2f(b.x) + h2f(d.x);
  o.y += h2f(a.y) + h2f(b.y) + h2f(d.y);
  o.z += h2f(a.z) + h2f(b.z) + h2f(d.z);
  o.w += h2f(a.w) + h2f(b.w) + h2f(d.w);
  ((float4*)(out + (size_t)r * 1024))[c] = o;
}

// ---------------- launch ----------------
extern "C" void kernel_launch(void* const* d_in, const int* in_sizes, int n_in,
                              void* d_out, int out_size, void* d_ws, size_t ws_size,
                              hipStream_t stream) {
  const float* x  = (const float*)d_in[0];
  const float* Wq = (const float*)d_in[1];
  const float* Wk = (const float*)d_in[2];
  const float* Wv = (const float*)d_in[3];

  // ws layout (bytes):
  //   [0, 64M)   : S/P fp16, row r at [r*16K, r*16K+8K) (stride 8192 ushorts);
  //                ctx partial z=2 fp16 at [+8K,+10K), z=3 at [+12K,+14K)
  //   [64M, 80M) : QK fp16 [4096][2048] (q|k); dead after scores -> ctx partial z=1 fp16
  //   [80M, 88M) : vT fp16 [1024][4096]
  //   [88M, 96M) : xb fp16 [4096][1024]
  //   [96M,102M) : Wcat fp16 [3072][1024]
  char* ws = (char*)d_ws;
  unsigned short* Sh    = (unsigned short*)ws;                // fp16 S/P, row stride 8192
  unsigned short* Hp2   = (unsigned short*)(ws + 8192);       // fp16, ld 8192
  unsigned short* Hp3   = (unsigned short*)(ws + 12288);      // fp16, ld 8192
  unsigned short* QK    = (unsigned short*)(ws + 67108864);
  unsigned short* Hp1   = (unsigned short*)(ws + 67108864);   // fp16, ld 1024 (reuse after scores)
  unsigned short* vT    = (unsigned short*)(ws + 83886080);   // [1024][4096]
  unsigned short* xb    = (unsigned short*)(ws + 92274688);
  unsigned short* Wcat  = (unsigned short*)(ws + 100663296);

  cast_kernel<<<4096, 256, 0, stream>>>(x, xb, 1048576);
  cast3_kernel<<<3072, 256, 0, stream>>>(Wq, Wk, Wv, Wcat);

  // fused QKV: [4096][3072] = xb @ Wcat^T; q|k -> QK fp16, v -> vT (transposed)
  gemm8<2><<<dim3(12, 16, 1), 512, 0, stream>>>(
      xb, 1024, Wcat, 1024, 1024, 1.0f,
      nullptr, 0, nullptr, 0, nullptr, 0, nullptr, 0, QK, 2048, vT, 4096);

  // S = (q @ k^T) / 32  (fp16 out, row stride 8192)
  gemm8<1><<<dim3(16, 16, 1), 512, 0, stream>>>(
      QK, 2048, QK + 1024, 2048, 1024, 0.03125f,
      nullptr, 0, nullptr, 0, nullptr, 0, nullptr, 0, Sh, 8192, nullptr, 0);

  softmax_rows<<<4096, 256, 0, stream>>>(Sh);

  // context = (P·512/512) @ vT^T; split-K=4: z=0 -> fp32 d_out, z=1..3 -> fp16 partials
  gemm8<0><<<dim3(4, 16, 4), 512, 0, stream>>>(
      Sh, 8192, vT, 4096, 1024, 1.0f / 512.0f,
      (float*)d_out, 1024, Hp1, 1024, Hp2, 8192, Hp3, 8192, nullptr, 0, nullptr, 0);
  combine4<<<4096, 256, 0, stream>>>((float*)d_out, Hp1, Hp2, Hp3);
}

// Round 11
// 152.859 us; speedup vs baseline: 1.9631x; 1.0102x over previous
//
#include <hip/hip_runtime.h>

typedef __attribute__((ext_vector_type(4))) float f32x4;
typedef __attribute__((ext_vector_type(8))) short short8;
typedef _Float16 half8 __attribute__((ext_vector_type(8)));

__device__ __forceinline__ unsigned short f2h(float f) {
  _Float16 h = (_Float16)f;                       // RTN
  return __builtin_bit_cast(unsigned short, h);
}
__device__ __forceinline__ float h2f(unsigned short u) {
  return (float)__builtin_bit_cast(_Float16, u);
}

// ---------------- cast fp32 -> fp16 (stored as ushort), 4 elems/thread ----------------
__global__ __launch_bounds__(256) void cast_kernel(const float* __restrict__ in,
                                                   unsigned short* __restrict__ out,
                                                   int n4) {
  int i = blockIdx.x * 256 + threadIdx.x;
  if (i >= n4) return;
  float4 v = ((const float4*)in)[i];
  ushort4 o;
  o.x = f2h(v.x); o.y = f2h(v.y); o.z = f2h(v.z); o.w = f2h(v.w);
  ((ushort4*)out)[i] = o;
}

// ---------------- cast 3 weight matrices into contiguous Wcat (one launch) ----------------
// Each W is 1024x1024 fp32 = 1048576 elems; segment s of Wcat starts at s*1048576 ushorts.
__global__ __launch_bounds__(256) void cast3_kernel(const float* __restrict__ w0,
                                                    const float* __restrict__ w1,
                                                    const float* __restrict__ w2,
                                                    unsigned short* __restrict__ out) {
  const int b = blockIdx.x;                  // 0..3071; 1024 blocks per segment
  const int seg = b >> 10;
  const float* src = (seg == 0) ? w0 : (seg == 1) ? w1 : w2;
  const int i = (b & 1023) * 256 + threadIdx.x;       // float4 index, < 262144 per segment
  float4 v = ((const float4*)src)[i];
  ushort4 o;
  o.x = f2h(v.x); o.y = f2h(v.y); o.z = f2h(v.z); o.w = f2h(v.w);
  ((ushort4*)(out + (size_t)seg * 1048576))[i] = o;
}

// ======================= 128x256 single-buffered NT GEMM (fp16) =======================
// C[m][n] = alpha * sum_k A[m][k]*B[n][k].  BM=128, BN=256, BK=64, 8 waves (2M x 4N),
// 48KB LDS (A 16KB + B 2x16KB halves) -> 2-3 blocks/CU resident. m97-style loop:
//   stage tile u -> vmcnt(0)+barrier -> read frags -> 32 MFMA/wave -> barrier.
// Exposed HBM drain per tile is hidden by the co-resident block(s) (m114 overlap).
// LDS swizzle: elem ^= (row&7)<<3 — conflict-free b128 column reads (verified r4).
// MODE 0: blockIdx.z in [0,4): z=0 -> fp32 C0/ldc0, z=1..3 -> fp16 H1..H3/ldh  [ctx]
// MODE 1: fp16 out to Cqk/ldqk                                                 [scores]
// MODE 2: QKV: cols [0,2048) -> fp16 Cqk; cols [2048,3072) -> transposed CvT via LDS.
template <int MODE>
__global__ __launch_bounds__(512, 4) void gemm8(
    const unsigned short* __restrict__ A, int lda,
    const unsigned short* __restrict__ B, int ldb,
    int ksplit, float alpha,
    float* __restrict__ C0, int ldc0,
    unsigned short* __restrict__ H1, int ldh1,
    unsigned short* __restrict__ H2, int ldh2,
    unsigned short* __restrict__ H3, int ldh3,
    unsigned short* __restrict__ Cqk, int ldqk,
    unsigned short* __restrict__ CvT, int ldvt) {
  // 48 KB: A tile [0,8192), B half0 [8192,16384), B half1 [16384,24576) (ushort idx).
  // MODE2 epilogue reuses [0, 17408) for the 128x128 transpose staging (stride 136).
  __shared__ __attribute__((aligned(16))) unsigned short lds[24576];

  const int t    = threadIdx.x;
  const int lane = t & 63;
  const int wave = t >> 6;
  const int wr   = wave >> 2;        // 0..1  (M: 64-row half)
  const int wc   = wave & 3;         // 0..3  (N: 64-col quarter)

  // XCD-aware bijective swizzle on the xy plane (nwg % 8 == 0 for all our grids)
  const int nx   = gridDim.x;
  const int nwg  = nx * gridDim.y;
  const int orig = blockIdx.y * nx + blockIdx.x;
  const int wg   = (orig & 7) * (nwg >> 3) + (orig >> 3);
  const int bm   = (wg / nx) * 128;
  const int bn   = (wg % nx) * 256;

  const int kbeg = blockIdx.z * ksplit;
  const int NT   = ksplit >> 6;

  const unsigned short* gA = A + (size_t)bm * lda;
  const unsigned short* gB = B + (size_t)bn * ldb;

  // stage one 128x64 half-tile: linear LDS dest (t*16B + j*8KB), inverse-swizzled source
  auto stage = [&](const unsigned short* gbase, int ld, int k0, unsigned short* dst) {
#pragma unroll
    for (int j = 0; j < 2; ++j) {
      const int de = t * 8 + j * 4096;                 // dest elem (row = de>>6, k = de&63)
      const int se = de ^ (((de >> 6) & 7) << 3);      // pre-swizzled source elem
      __builtin_amdgcn_global_load_lds(
          (const __attribute__((address_space(1))) void*)(gbase + (size_t)(se >> 6) * ld + k0 + (se & 63)),
          (__attribute__((address_space(3))) void*)(dst + de),
          16, 0, 0);
    }
  };

  f32x4 acc[4][4];
#pragma unroll
  for (int i = 0; i < 4; ++i)
#pragma unroll
    for (int j = 0; j < 4; ++j)
      acc[i][j] = (f32x4){0.f, 0.f, 0.f, 0.f};

  const int frow  = lane & 15;
  const int fk    = (lane >> 4) * 8;
  const int brow0 = (wc & 1) * 64;

  for (int u = 0; u < NT; ++u) {
    const int k0 = kbeg + u * 64;
    // stage the full tile: A (128x64) + B (256x64 as two 128-row halves)
    stage(gA,                     lda, k0, lds);
    stage(gB,                     ldb, k0, lds + 8192);
    stage(gB + (size_t)128 * ldb, ldb, k0, lds + 16384);
    asm volatile("s_waitcnt vmcnt(0)" ::: "memory");
    __builtin_amdgcn_s_barrier();

    const unsigned short* Bb = lds + 8192 + (wc >> 1) * 8192;
    half8 bf[4][2];
#pragma unroll
    for (int n = 0; n < 4; ++n)
#pragma unroll
      for (int ks = 0; ks < 2; ++ks) {
        const int row = brow0 + n * 16 + frow;
        const int e = (row * 64 + ks * 32 + fk) ^ ((row & 7) << 3);
        bf[n][ks] = *(const half8*)(const void*)(Bb + e);
      }

    __builtin_amdgcn_s_setprio(1);
#pragma unroll
    for (int m = 0; m < 4; ++m) {
      const int row = wr * 64 + m * 16 + frow;
      const half8 a0 = *(const half8*)(const void*)(lds + ((row * 64 + fk) ^ ((row & 7) << 3)));
      const half8 a1 = *(const half8*)(const void*)(lds + ((row * 64 + 32 + fk) ^ ((row & 7) << 3)));
#pragma unroll
      for (int n = 0; n < 4; ++n)
        acc[m][n] = __builtin_amdgcn_mfma_f32_16x16x32_f16(a0, bf[n][0], acc[m][n], 0, 0, 0);
#pragma unroll
      for (int n = 0; n < 4; ++n)
        acc[m][n] = __builtin_amdgcn_mfma_f32_16x16x32_f16(a1, bf[n][1], acc[m][n], 0, 0, 0);
    }
    __builtin_amdgcn_s_setprio(0);
    __builtin_amdgcn_s_barrier();   // all waves done reading before next stage overwrites
  }

  // ---- epilogue ----
  if constexpr (MODE == 0) {
#pragma unroll
    for (int m = 0; m < 4; ++m) {
#pragma unroll
      for (int n = 0; n < 4; ++n) {
        const int row0 = bm + wr * 64 + m * 16 + (lane >> 4) * 4;
        const int col  = bn + wc * 64 + n * 16 + (lane & 15);
        if (blockIdx.z == 0) {
#pragma unroll
          for (int j = 0; j < 4; ++j)
            C0[(size_t)(row0 + j) * ldc0 + col] = acc[m][n][j] * alpha;
        } else {
          unsigned short* H; int ldh;
          if      (blockIdx.z == 1) { H = H1; ldh = ldh1; }
          else if (blockIdx.z == 2) { H = H2; ldh = ldh2; }
          else                      { H = H3; ldh = ldh3; }
#pragma unroll
          for (int j = 0; j < 4; ++j)
            H[(size_t)(row0 + j) * ldh + col] = f2h(acc[m][n][j] * alpha);
        }
      }
    }
  } else if constexpr (MODE == 1) {
#pragma unroll
    for (int m = 0; m < 4; ++m)
#pragma unroll
      for (int n = 0; n < 4; ++n) {
        const int row0 = bm + wr * 64 + m * 16 + (lane >> 4) * 4;
        const int col  = bn + wc * 64 + n * 16 + (lane & 15);
#pragma unroll
        for (int j = 0; j < 4; ++j)
          Cqk[(size_t)(row0 + j) * ldqk + col] = f2h(acc[m][n][j] * alpha);
      }
  } else {
    if (bn < 2048) {
#pragma unroll
      for (int m = 0; m < 4; ++m)
#pragma unroll
        for (int n = 0; n < 4; ++n) {
          const int row0 = bm + wr * 64 + m * 16 + (lane >> 4) * 4;
          const int col  = bn + wc * 64 + n * 16 + (lane & 15);
#pragma unroll
          for (int j = 0; j < 4; ++j)
            Cqk[(size_t)(row0 + j) * ldqk + col] = f2h(acc[m][n][j] * alpha);
        }
    } else {
      // vT via LDS transpose: two 128-col passes; T[cl][r] ushort, stride 136 (16B rows).
#pragma unroll
      for (int p = 0; p < 2; ++p) {
        __syncthreads();
        if ((wc >> 1) == p) {
#pragma unroll
          for (int m = 0; m < 4; ++m)
#pragma unroll
            for (int n = 0; n < 4; ++n) {
              const int cl = (wc & 1) * 64 + n * 16 + (lane & 15);   // col within half
              const int r  = wr * 64 + m * 16 + (lane >> 4) * 4;     // local seq row
              ushort4 o;
              o.x = f2h(acc[m][n][0] * alpha);
              o.y = f2h(acc[m][n][1] * alpha);
              o.z = f2h(acc[m][n][2] * alpha);
              o.w = f2h(acc[m][n][3] * alpha);
              *(ushort4*)(lds + cl * 136 + r) = o;
            }
        }
        __syncthreads();
        // copy out: t -> cl = t>>2 (0..127), rows (t&3)*32 .. +31 (coalesced 64B/thread)
        const int cl = t >> 2, roff = (t & 3) * 32;
        const unsigned short* src = lds + cl * 136 + roff;
        unsigned short* dst = CvT + (size_t)(bn - 2048 + p * 128 + cl) * ldvt + bm + roff;
#pragma unroll
        for (int i = 0; i < 4; ++i)
          *(short8*)(dst + i * 8) = *(const short8*)(src + i * 8);
      }
    }
  }
}

// ---------------- row softmax over fp16 S rows (stride 8192 ushorts); in-place ----------------
// P written pre-scaled by 512 (ctx GEMM uses alpha = 1/512) to stay out of fp16 subnormals.
__global__ __launch_bounds__(256) void softmax_rows(unsigned short* __restrict__ S) {
  const int row  = blockIdx.x;
  const int t    = threadIdx.x;
  const int lane = t & 63;
  const int wave = t >> 6;

  unsigned short* base = S + (size_t)row * 8192;
  ushort4 v[4];  // 16 halves/thread, contiguous 32B at t*16
  float f[16];
  float m = -3.0e38f;
#pragma unroll
  for (int i = 0; i < 4; ++i) {
    v[i] = ((const ushort4*)(base + t * 16))[i];
    f[4 * i + 0] = h2f(v[i].x);
    f[4 * i + 1] = h2f(v[i].y);
    f[4 * i + 2] = h2f(v[i].z);
    f[4 * i + 3] = h2f(v[i].w);
    m = fmaxf(m, fmaxf(fmaxf(f[4 * i + 0], f[4 * i + 1]), fmaxf(f[4 * i + 2], f[4 * i + 3])));
  }
#pragma unroll
  for (int off = 1; off < 64; off <<= 1)
    m = fmaxf(m, __shfl_xor(m, off));

  __shared__ float red[4];
  if (lane == 0) red[wave] = m;
  __syncthreads();
  m = fmaxf(fmaxf(red[0], red[1]), fmaxf(red[2], red[3]));
  __syncthreads();

  float s = 0.f;
#pragma unroll
  for (int i = 0; i < 16; ++i) {
    f[i] = __expf(f[i] - m);
    s += f[i];
  }
#pragma unroll
  for (int off = 1; off < 64; off <<= 1)
    s += __shfl_xor(s, off);
  if (lane == 0) red[wave] = s;
  __syncthreads();
  s = red[0] + red[1] + red[2] + red[3];
  const float inv = 512.0f / s;

#pragma unroll
  for (int i = 0; i < 4; ++i) {
    ushort4 o;
    o.x = f2h(f[4 * i + 0] * inv);
    o.y = f2h(f[4 * i + 1] * inv);
    o.z = f2h(f[4 * i + 2] * inv);
    o.w = f2h(f[4 * i + 3] * inv);
    ((ushort4*)(base + t * 16))[i] = o;
  }
}

// ---------------- combine split-K=4 partials: out += h2f(p1)+h2f(p2)+h2f(p3) ----------------
// out fp32 ld 1024; p1 fp16 ld 1024; p2/p3 fp16 ld 8192 (odd halves of S rows)
__global__ __launch_bounds__(256) void combine4(float* __restrict__ out,
                                                const unsigned short* __restrict__ p1,
                                                const unsigned short* __restrict__ p2,
                                                const unsigned short* __restrict__ p3) {
  const int r = blockIdx.x, c = threadIdx.x;
  float4 o = ((float4*)(out + (size_t)r * 1024))[c];
  ushort4 a = ((const ushort4*)(p1 + (size_t)r * 1024))[c];
  ushort4 b = ((const ushort4*)(p2 + (size_t)r * 8192))[c];
  ushort4 d = ((const ushort4*)(p3 + (size_t)r * 8192))[c];
  o.x += h2f(a.x) + h2f(b.x) + h2f(d.x);
  o.y += h2f(a.y) + h2f(b.y) + h2f(d.y);
  o.z += h2f(a.z) + h2f(b.z) + h2f(d.z);
  o.w += h2f(a.w) + h2f(b.w) + h2f(d.w);
  ((float4*)(out + (size_t)r * 1024))[c] = o;
}

// ---------------- launch ----------------
extern "C" void kernel_launch(void* const* d_in, const int* in_sizes, int n_in,
                              void* d_out, int out_size, void* d_ws, size_t ws_size,
                              hipStream_t stream) {
  const float* x  = (const float*)d_in[0];
  const float* Wq = (const float*)d_in[1];
  const float* Wk = (const float*)d_in[2];
  const float* Wv = (const float*)d_in[3];

  // ws layout (bytes):
  //   [0, 64M)   : S/P fp16, row r at [r*16K, r*16K+8K) (stride 8192 ushorts);
  //                ctx partial z=2 fp16 at [+8K,+10K), z=3 at [+12K,+14K)
  //   [64M, 80M) : QK fp16 [4096][2048] (q|k); dead after scores -> ctx partial z=1 fp16
  //   [80M, 88M) : vT fp16 [1024][4096]
  //   [88M, 96M) : xb fp16 [4096][1024]
  //   [96M,102M) : Wcat fp16 [3072][1024]
  char* ws = (char*)d_ws;
  unsigned short* Sh    = (unsigned short*)ws;                // fp16 S/P, row stride 8192
  unsigned short* Hp2   = (unsigned short*)(ws + 8192);       // fp16, ld 8192
  unsigned short* Hp3   = (unsigned short*)(ws + 12288);      // fp16, ld 8192
  unsigned short* QK    = (unsigned short*)(ws + 67108864);
  unsigned short* Hp1   = (unsigned short*)(ws + 67108864);   // fp16, ld 1024 (reuse after scores)
  unsigned short* vT    = (unsigned short*)(ws + 83886080);   // [1024][4096]
  unsigned short* xb    = (unsigned short*)(ws + 92274688);
  unsigned short* Wcat  = (unsigned short*)(ws + 100663296);

  cast_kernel<<<4096, 256, 0, stream>>>(x, xb, 1048576);
  cast3_kernel<<<3072, 256, 0, stream>>>(Wq, Wk, Wv, Wcat);

  // fused QKV: [4096][3072] = xb @ Wcat^T; q|k -> QK fp16, v -> vT (transposed)
  gemm8<2><<<dim3(12, 32, 1), 512, 0, stream>>>(
      xb, 1024, Wcat, 1024, 1024, 1.0f,
      nullptr, 0, nullptr, 0, nullptr, 0, nullptr, 0, QK, 2048, vT, 4096);

  // S = (q @ k^T) / 32  (fp16 out, row stride 8192)
  gemm8<1><<<dim3(16, 32, 1), 512, 0, stream>>>(
      QK, 2048, QK + 1024, 2048, 1024, 0.03125f,
      nullptr, 0, nullptr, 0, nullptr, 0, nullptr, 0, Sh, 8192, nullptr, 0);

  softmax_rows<<<4096, 256, 0, stream>>>(Sh);

  // context = (P·512/512) @ vT^T; split-K=4: z=0 -> fp32 d_out, z=1..3 -> fp16 partials
  gemm8<0><<<dim3(4, 32, 4), 512, 0, stream>>>(
      Sh, 8192, vT, 4096, 1024, 1.0f / 512.0f,
      (float*)d_out, 1024, Hp1, 1024, Hp2, 8192, Hp3, 8192, nullptr, 0, nullptr, 0);
  combine4<<<4096, 256, 0, stream>>>((float*)d_out, Hp1, Hp2, Hp3);
}